// Round 3
// baseline (667.801 us; speedup 1.0000x reference)
//
#include <hip/hip_runtime.h>
#include <math.h>

#define N_NODES 50000
#define N_EDGES 800000
#define FDIM 128
#define KCLS 10

// ---------------- CSR build ----------------

__global__ void k_count(const int* __restrict__ dst, int* __restrict__ indeg, int e_total) {
    int e = blockIdx.x * 256 + threadIdx.x;
    if (e < e_total) atomicAdd(&indeg[dst[e]], 1);
}

__global__ __launch_bounds__(1024) void k_scan_block(const int* __restrict__ in, int* __restrict__ excl,
                                                     int* __restrict__ bsum, int n) {
    __shared__ int sh[1024];
    int t = threadIdx.x;
    int g = blockIdx.x * 1024 + t;
    int v = (g < n) ? in[g] : 0;
    sh[t] = v;
    __syncthreads();
    for (int d = 1; d < 1024; d <<= 1) {
        int x = (t >= d) ? sh[t - d] : 0;
        __syncthreads();
        sh[t] += x;
        __syncthreads();
    }
    if (g < n) excl[g] = sh[t] - v;
    if (t == 1023) bsum[blockIdx.x] = sh[t];
}

__global__ void k_scan_small(int* bsum, int nb) {
    if (threadIdx.x == 0 && blockIdx.x == 0) {
        int run = 0;
        for (int i = 0; i < nb; i++) { int v = bsum[i]; bsum[i] = run; run += v; }
    }
}

__global__ __launch_bounds__(1024) void k_scan_add(int* __restrict__ offs, const int* __restrict__ bsum,
                                                   int* __restrict__ cursor, int n, int e_total) {
    int g = blockIdx.x * 1024 + threadIdx.x;
    if (g < n) {
        int v = offs[g] + bsum[blockIdx.x];
        offs[g] = v;
        cursor[g] = v;
    }
    if (g == 0) offs[n] = e_total;
}

__global__ void k_scatter(const int* __restrict__ src, const int* __restrict__ dst,
                          int* __restrict__ cursor, int* __restrict__ seid, int* __restrict__ ssrc, int e_total) {
    int e = blockIdx.x * 256 + threadIdx.x;
    if (e < e_total) {
        int d = dst[e];
        int p = atomicAdd(&cursor[d], 1);
        seid[p] = e;
        ssrc[p] = src[e];
    }
}

// copy edge_attr into CSR (sorted) order: coalesced writes, gathered reads
__global__ void k_gather_ea(const int* __restrict__ seid, const float* __restrict__ edge_attr,
                            float* __restrict__ sea, int e_total) {
    int p = blockIdx.x * 256 + threadIdx.x;
    int ep = p >> 2, q = p & 3;
    if (ep < e_total) {
        int eid = seid[ep];
        ((float4*)sea)[ep * 4 + q] = ((const float4*)edge_attr)[eid * 4 + q];
    }
}

// ---------------- h = x @ Wp + bp  ([N,64]@[64,128]) ----------------

__global__ __launch_bounds__(256) void k_proj(const float* __restrict__ x, const float* __restrict__ Wp,
                                              const float* __restrict__ bp, float* __restrict__ h, int n) {
    __shared__ float shx[32 * 64];
    __shared__ float shw[64 * 128];
    int t = threadIdx.x;
    int row0 = blockIdx.x * 32;
    int nrows = min(32, n - row0);

    for (int i = t; i < 64 * 128 / 4; i += 256)
        ((float4*)shw)[i] = ((const float4*)Wp)[i];
    for (int i = t; i < 32 * 64 / 4; i += 256) {
        int r = i >> 4;
        float4 v = make_float4(0.f, 0.f, 0.f, 0.f);
        if (r < nrows) v = ((const float4*)x)[row0 * 16 + i];
        ((float4*)shx)[i] = v;
    }
    __syncthreads();

    int tr = (t >> 5) * 4;
    int tc = (t & 31) * 4;
    float acc[4][4];
    float4 b4 = *(const float4*)&bp[tc];
#pragma unroll
    for (int j = 0; j < 4; j++) { acc[j][0] = b4.x; acc[j][1] = b4.y; acc[j][2] = b4.z; acc[j][3] = b4.w; }

    for (int k = 0; k < 64; k++) {
        float4 w = *(float4*)&shw[k * 128 + tc];
#pragma unroll
        for (int j = 0; j < 4; j++) {
            float a = shx[(tr + j) * 64 + k];
            acc[j][0] = fmaf(a, w.x, acc[j][0]);
            acc[j][1] = fmaf(a, w.y, acc[j][1]);
            acc[j][2] = fmaf(a, w.z, acc[j][2]);
            acc[j][3] = fmaf(a, w.w, acc[j][3]);
        }
    }
#pragma unroll
    for (int j = 0; j < 4; j++) {
        int r = row0 + tr + j;
        if (r < n) {
            float4 o = make_float4(acc[j][0], acc[j][1], acc[j][2], acc[j][3]);
            *(float4*)&h[r * 128 + tc] = o;
        }
    }
}

// ---------------- fused LayerNorm + dual GEMM ----------------

__global__ __launch_bounds__(256) void k_ln_gemm(const float* __restrict__ h,
                                                 const float* __restrict__ lng, const float* __restrict__ lnb,
                                                 const float* __restrict__ Wl, const float* __restrict__ bl,
                                                 const float* __restrict__ Wr, const float* __restrict__ br,
                                                 float* __restrict__ xl, float* __restrict__ xr, int n) {
    __shared__ float shn[32 * 128];
    __shared__ float shwl[32 * 128];
    __shared__ float shwr[32 * 128];
    __shared__ float smu[32], srs[32];
    int t = threadIdx.x;
    int row0 = blockIdx.x * 32;
    int nrows = min(32, n - row0);

    for (int i = t; i < 1024; i += 256) {
        int r = i >> 5;
        float4 v = make_float4(0.f, 0.f, 0.f, 0.f);
        if (r < nrows) v = ((const float4*)h)[row0 * 32 + i];
        ((float4*)shn)[i] = v;
    }
    __syncthreads();

    {
        int r = t >> 3, sl = t & 7;
        float s = 0.f, ss = 0.f;
        for (int c = sl; c < 128; c += 8) {
            float v = shn[r * 128 + c];
            s += v; ss += v * v;
        }
#pragma unroll
        for (int o = 1; o < 8; o <<= 1) { s += __shfl_xor(s, o, 64); ss += __shfl_xor(ss, o, 64); }
        if (sl == 0) {
            float mu = s * (1.f / 128.f);
            float var = ss * (1.f / 128.f) - mu * mu;
            smu[r] = mu;
            srs[r] = rsqrtf(var + 1e-5f);
        }
    }
    __syncthreads();
    for (int i = t; i < 4096; i += 256) {
        int r = i >> 7, c = i & 127;
        shn[i] = (shn[i] - smu[r]) * srs[r] * lng[c] + lnb[c];
    }

    int tr = (t >> 5) * 4;
    int tc = (t & 31) * 4;
    float accl[4][4], accr[4][4];
    {
        float4 bl4 = *(const float4*)&bl[tc];
        float4 br4 = *(const float4*)&br[tc];
#pragma unroll
        for (int j = 0; j < 4; j++) {
            accl[j][0] = bl4.x; accl[j][1] = bl4.y; accl[j][2] = bl4.z; accl[j][3] = bl4.w;
            accr[j][0] = br4.x; accr[j][1] = br4.y; accr[j][2] = br4.z; accr[j][3] = br4.w;
        }
    }

    for (int kb = 0; kb < 4; kb++) {
        __syncthreads();
        for (int i = t; i < 1024; i += 256) {
            ((float4*)shwl)[i] = ((const float4*)Wl)[kb * 1024 + i];
            ((float4*)shwr)[i] = ((const float4*)Wr)[kb * 1024 + i];
        }
        __syncthreads();
#pragma unroll 8
        for (int kk = 0; kk < 32; kk++) {
            int k = kb * 32 + kk;
            float4 wl4 = *(float4*)&shwl[kk * 128 + tc];
            float4 wr4 = *(float4*)&shwr[kk * 128 + tc];
#pragma unroll
            for (int j = 0; j < 4; j++) {
                float a = shn[(tr + j) * 128 + k];
                accl[j][0] = fmaf(a, wl4.x, accl[j][0]);
                accl[j][1] = fmaf(a, wl4.y, accl[j][1]);
                accl[j][2] = fmaf(a, wl4.z, accl[j][2]);
                accl[j][3] = fmaf(a, wl4.w, accl[j][3]);
                accr[j][0] = fmaf(a, wr4.x, accr[j][0]);
                accr[j][1] = fmaf(a, wr4.y, accr[j][1]);
                accr[j][2] = fmaf(a, wr4.z, accr[j][2]);
                accr[j][3] = fmaf(a, wr4.w, accr[j][3]);
            }
        }
    }
#pragma unroll
    for (int j = 0; j < 4; j++) {
        int r = row0 + tr + j;
        if (r < n) {
            float4 ol = make_float4(accl[j][0], accl[j][1], accl[j][2], accl[j][3]);
            float4 orr = make_float4(accr[j][0], accr[j][1], accr[j][2], accr[j][3]);
            *(float4*)&xl[r * 128 + tc] = ol;
            *(float4*)&xr[r * 128 + tc] = orr;
        }
    }
}

// ---------------- GAT aggregate v3 ----------------
// No online max (logits are tiny: |l| << 88, exp() safe; softmax is shift-
// invariant so result identical). 4-edge unroll: 4 independent xl-gathers in
// flight, one 5-level butterfly pass over 4 interleaved logits.

__device__ __forceinline__ void ee16(const float4& c0, const float4& c1, const float4& c2, const float4& c3,
                                     const float2* we, float& e0, float& e1) {
    e0 = fmaf(c0.x, we[0].x, e0);  e1 = fmaf(c0.x, we[0].y, e1);
    e0 = fmaf(c0.y, we[1].x, e0);  e1 = fmaf(c0.y, we[1].y, e1);
    e0 = fmaf(c0.z, we[2].x, e0);  e1 = fmaf(c0.z, we[2].y, e1);
    e0 = fmaf(c0.w, we[3].x, e0);  e1 = fmaf(c0.w, we[3].y, e1);
    e0 = fmaf(c1.x, we[4].x, e0);  e1 = fmaf(c1.x, we[4].y, e1);
    e0 = fmaf(c1.y, we[5].x, e0);  e1 = fmaf(c1.y, we[5].y, e1);
    e0 = fmaf(c1.z, we[6].x, e0);  e1 = fmaf(c1.z, we[6].y, e1);
    e0 = fmaf(c1.w, we[7].x, e0);  e1 = fmaf(c1.w, we[7].y, e1);
    e0 = fmaf(c2.x, we[8].x, e0);  e1 = fmaf(c2.x, we[8].y, e1);
    e0 = fmaf(c2.y, we[9].x, e0);  e1 = fmaf(c2.y, we[9].y, e1);
    e0 = fmaf(c2.z, we[10].x, e0); e1 = fmaf(c2.z, we[10].y, e1);
    e0 = fmaf(c2.w, we[11].x, e0); e1 = fmaf(c2.w, we[11].y, e1);
    e0 = fmaf(c3.x, we[12].x, e0); e1 = fmaf(c3.x, we[12].y, e1);
    e0 = fmaf(c3.y, we[13].x, e0); e1 = fmaf(c3.y, we[13].y, e1);
    e0 = fmaf(c3.z, we[14].x, e0); e1 = fmaf(c3.z, we[14].y, e1);
    e0 = fmaf(c3.w, we[15].x, e0); e1 = fmaf(c3.w, we[15].y, e1);
}

__device__ __forceinline__ float lrelu(float v) { return v > 0.f ? v : 0.2f * v; }

template <bool SORTED>
__global__ __launch_bounds__(256) void k_gat_agg3(const float* __restrict__ xl, const float* __restrict__ xr,
                                                  const float* __restrict__ eattr,
                                                  const int* __restrict__ offs,
                                                  const int* __restrict__ seid, const int* __restrict__ ssrc,
                                                  const float* __restrict__ We, const float* __restrict__ att,
                                                  const float* __restrict__ bout, float* __restrict__ h, int n) {
    int wid = threadIdx.x >> 6;
    int lane = threadIdx.x & 63;
    int node = blockIdx.x * 4 + wid;
    if (node >= n) return;

    int chb = (lane >> 5) * 64 + (lane & 31) * 2;

    float2 we[16];
#pragma unroll
    for (int k = 0; k < 16; k++) we[k] = *(const float2*)&We[k * 128 + chb];
    float2 av = *(const float2*)&att[chb];
    float2 xr2 = *(const float2*)&xr[node * 128 + chb];
    float2 bo = *(const float2*)&bout[chb];

    int s = offs[node], e = offs[node + 1];
    float den = 0.f, A0 = 0.f, A1 = 0.f;

    int j = s;
    for (; j + 4 <= e; j += 4) {
        int sa = ssrc[j], sb = ssrc[j + 1], sc2 = ssrc[j + 2], sd = ssrc[j + 3];
        float2 lxa = *(const float2*)&xl[sa * 128 + chb];
        float2 lxb = *(const float2*)&xl[sb * 128 + chb];
        float2 lxc = *(const float2*)&xl[sc2 * 128 + chb];
        float2 lxd = *(const float2*)&xl[sd * 128 + chb];
        const float4* eaA = (const float4*)&eattr[(size_t)(SORTED ? j : seid[j]) * 16];
        const float4* eaB = (const float4*)&eattr[(size_t)(SORTED ? j + 1 : seid[j + 1]) * 16];
        const float4* eaC = (const float4*)&eattr[(size_t)(SORTED ? j + 2 : seid[j + 2]) * 16];
        const float4* eaD = (const float4*)&eattr[(size_t)(SORTED ? j + 3 : seid[j + 3]) * 16];

        float ea0 = 0.f, ea1 = 0.f, eb0 = 0.f, eb1 = 0.f;
        float ec0 = 0.f, ec1 = 0.f, ed0 = 0.f, ed1 = 0.f;
        ee16(eaA[0], eaA[1], eaA[2], eaA[3], we, ea0, ea1);
        ee16(eaB[0], eaB[1], eaB[2], eaB[3], we, eb0, eb1);
        ee16(eaC[0], eaC[1], eaC[2], eaC[3], we, ec0, ec1);
        ee16(eaD[0], eaD[1], eaD[2], eaD[3], we, ed0, ed1);

        float pa = lrelu(lxa.x + xr2.x + ea0) * av.x + lrelu(lxa.y + xr2.y + ea1) * av.y;
        float pb = lrelu(lxb.x + xr2.x + eb0) * av.x + lrelu(lxb.y + xr2.y + eb1) * av.y;
        float pc = lrelu(lxc.x + xr2.x + ec0) * av.x + lrelu(lxc.y + xr2.y + ec1) * av.y;
        float pd = lrelu(lxd.x + xr2.x + ed0) * av.x + lrelu(lxd.y + xr2.y + ed1) * av.y;
#pragma unroll
        for (int o = 1; o <= 16; o <<= 1) {
            pa += __shfl_xor(pa, o, 64);
            pb += __shfl_xor(pb, o, 64);
            pc += __shfl_xor(pc, o, 64);
            pd += __shfl_xor(pd, o, 64);
        }
        float wa = __expf(pa), wb = __expf(pb), wc = __expf(pc), wd = __expf(pd);
        den += (wa + wb) + (wc + wd);
        A0 = fmaf(wa, lxa.x, fmaf(wb, lxb.x, fmaf(wc, lxc.x, fmaf(wd, lxd.x, A0))));
        A1 = fmaf(wa, lxa.y, fmaf(wb, lxb.y, fmaf(wc, lxc.y, fmaf(wd, lxd.y, A1))));
    }
    for (; j < e; j++) {
        int sa = ssrc[j];
        const float4* eaA = (const float4*)&eattr[(size_t)(SORTED ? j : seid[j]) * 16];
        float2 lxa = *(const float2*)&xl[sa * 128 + chb];
        float ea0 = 0.f, ea1 = 0.f;
        ee16(eaA[0], eaA[1], eaA[2], eaA[3], we, ea0, ea1);
        float pa = lrelu(lxa.x + xr2.x + ea0) * av.x + lrelu(lxa.y + xr2.y + ea1) * av.y;
#pragma unroll
        for (int o = 1; o <= 16; o <<= 1) pa += __shfl_xor(pa, o, 64);
        float wa = __expf(pa);
        den += wa;
        A0 = fmaf(wa, lxa.x, A0);
        A1 = fmaf(wa, lxa.y, A1);
    }

    float inv = (e > s) ? (1.f / den) : 0.f;
    float hg0 = fmaxf(fmaf(A0, inv, bo.x), 0.f);
    float hg1 = fmaxf(fmaf(A1, inv, bo.y), 0.f);
    float2* hp = (float2*)&h[node * 128 + chb];
    float2 hv = *hp;
    hv.x += hg0;
    hv.y += hg1;
    *hp = hv;
}

// ---------------- classifier + embedding write ----------------

__global__ __launch_bounds__(256) void k_cls(const float* __restrict__ h, const float* __restrict__ Wc,
                                             const float* __restrict__ bc,
                                             float* __restrict__ out_cls, float* __restrict__ out_emb, int n) {
    int wid = threadIdx.x >> 6;
    int lane = threadIdx.x & 63;
    int node = blockIdx.x * 4 + wid;
    if (node >= n) return;
    float h0 = h[(size_t)node * 128 + lane];
    float h1 = h[(size_t)node * 128 + 64 + lane];
    float p[10];
#pragma unroll
    for (int k = 0; k < 10; k++) p[k] = h0 * Wc[lane * 10 + k] + h1 * Wc[(64 + lane) * 10 + k];
#pragma unroll
    for (int o = 32; o; o >>= 1) {
#pragma unroll
        for (int k = 0; k < 10; k++) p[k] += __shfl_xor(p[k], o, 64);
    }
    if (lane == 0) {
#pragma unroll
        for (int k = 0; k < 10; k++) out_cls[(size_t)node * 10 + k] = p[k] + bc[k];
    }
    out_emb[(size_t)node * 128 + lane] = h0;
    out_emb[(size_t)node * 128 + 64 + lane] = h1;
}

extern "C" void kernel_launch(void* const* d_in, const int* in_sizes, int n_in,
                              void* d_out, int out_size, void* d_ws, size_t ws_size,
                              hipStream_t stream) {
    const float* x         = (const float*)d_in[0];
    const int*   edge_idx  = (const int*)d_in[1];
    const float* edge_attr = (const float*)d_in[2];
    const float* Wp        = (const float*)d_in[3];
    const float* bp        = (const float*)d_in[4];
    const float* lng       = (const float*)d_in[5];
    const float* lnb       = (const float*)d_in[6];
    const float* Wl        = (const float*)d_in[7];
    const float* bl        = (const float*)d_in[8];
    const float* Wr        = (const float*)d_in[9];
    const float* br        = (const float*)d_in[10];
    const float* We        = (const float*)d_in[11];
    const float* att       = (const float*)d_in[12];
    const float* bout      = (const float*)d_in[13];
    const float* Wc        = (const float*)d_in[14];
    const float* bc        = (const float*)d_in[15];

    const int N = N_NODES, E = N_EDGES;

    char* w = (char*)d_ws;
    size_t used = 0;
    auto take = [&](size_t bytes) -> void* {
        void* p = (void*)(w + used);
        used += (bytes + 255) & ~(size_t)255;
        return p;
    };
    float* h      = (float*)take((size_t)N * 128 * 4);
    float* xl     = (float*)take((size_t)N * 128 * 4);
    float* xr     = (float*)take((size_t)N * 128 * 4);
    int*   indeg  = (int*)take((size_t)N * 4);
    int*   offs   = (int*)take((size_t)(N + 1) * 4);
    int*   cursor = (int*)take((size_t)N * 4);
    int*   bsum   = (int*)take(64 * 4);
    int*   seid   = (int*)take((size_t)E * 4);
    int*   ssrc   = (int*)take((size_t)E * 4);
    float* sea    = (float*)take((size_t)E * 16 * 4);
    bool sorted_ok = (used <= ws_size);

    const int* srcArr = edge_idx;
    const int* dstArr = edge_idx + E;

    hipMemsetAsync(indeg, 0, (size_t)N * 4, stream);
    k_count<<<(E + 255) / 256, 256, 0, stream>>>(dstArr, indeg, E);
    int NB = (N + 1023) / 1024;
    k_scan_block<<<NB, 1024, 0, stream>>>(indeg, offs, bsum, N);
    k_scan_small<<<1, 64, 0, stream>>>(bsum, NB);
    k_scan_add<<<NB, 1024, 0, stream>>>(offs, bsum, cursor, N, E);
    k_scatter<<<(E + 255) / 256, 256, 0, stream>>>(srcArr, dstArr, cursor, seid, ssrc, E);
    if (sorted_ok)
        k_gather_ea<<<(E * 4 + 255) / 256, 256, 0, stream>>>(seid, edge_attr, sea, E);

    k_proj<<<(N + 31) / 32, 256, 0, stream>>>(x, Wp, bp, h, N);

    for (int i = 0; i < 2; i++) {
        k_ln_gemm<<<(N + 31) / 32, 256, 0, stream>>>(
            h, lng + i * 128, lnb + i * 128,
            Wl + (size_t)i * 128 * 128, bl + i * 128,
            Wr + (size_t)i * 128 * 128, br + i * 128,
            xl, xr, N);
        if (sorted_ok)
            k_gat_agg3<true><<<(N + 3) / 4, 256, 0, stream>>>(
                xl, xr, sea, offs, seid, ssrc,
                We + (size_t)i * 16 * 128, att + i * 128, bout + i * 128, h, N);
        else
            k_gat_agg3<false><<<(N + 3) / 4, 256, 0, stream>>>(
                xl, xr, edge_attr, offs, seid, ssrc,
                We + (size_t)i * 16 * 128, att + i * 128, bout + i * 128, h, N);
    }

    k_cls<<<(N + 3) / 4, 256, 0, stream>>>(h, Wc, bc, (float*)d_out, (float*)d_out + (size_t)N * KCLS, N);
}

// Round 4
// 616.731 us; speedup vs baseline: 1.0828x; 1.0828x over previous
//
#include <hip/hip_runtime.h>
#include <math.h>

#define N_NODES 50000
#define N_EDGES 800000
#define FDIM 128
#define KCLS 10

// ---------------- CSR build ----------------

__global__ void k_count(const int* __restrict__ dst, int* __restrict__ indeg, int e_total) {
    int e = blockIdx.x * 256 + threadIdx.x;
    if (e < e_total) atomicAdd(&indeg[dst[e]], 1);
}

__global__ __launch_bounds__(1024) void k_scan_block(const int* __restrict__ in, int* __restrict__ excl,
                                                     int* __restrict__ bsum, int n) {
    __shared__ int sh[1024];
    int t = threadIdx.x;
    int g = blockIdx.x * 1024 + t;
    int v = (g < n) ? in[g] : 0;
    sh[t] = v;
    __syncthreads();
    for (int d = 1; d < 1024; d <<= 1) {
        int x = (t >= d) ? sh[t - d] : 0;
        __syncthreads();
        sh[t] += x;
        __syncthreads();
    }
    if (g < n) excl[g] = sh[t] - v;
    if (t == 1023) bsum[blockIdx.x] = sh[t];
}

__global__ void k_scan_small(int* bsum, int nb) {
    if (threadIdx.x == 0 && blockIdx.x == 0) {
        int run = 0;
        for (int i = 0; i < nb; i++) { int v = bsum[i]; bsum[i] = run; run += v; }
    }
}

__global__ __launch_bounds__(1024) void k_scan_add(int* __restrict__ offs, const int* __restrict__ bsum,
                                                   int* __restrict__ cursor, int n, int e_total) {
    int g = blockIdx.x * 1024 + threadIdx.x;
    if (g < n) {
        int v = offs[g] + bsum[blockIdx.x];
        offs[g] = v;
        cursor[g] = v;
    }
    if (g == 0) offs[n] = e_total;
}

__global__ void k_scatter(const int* __restrict__ src, const int* __restrict__ dst,
                          int* __restrict__ cursor, int* __restrict__ seid, int* __restrict__ ssrc, int e_total) {
    int e = blockIdx.x * 256 + threadIdx.x;
    if (e < e_total) {
        int d = dst[e];
        int p = atomicAdd(&cursor[d], 1);
        seid[p] = e;
        ssrc[p] = src[e];
    }
}

// copy edge_attr into CSR (sorted) order: coalesced writes, gathered reads
__global__ void k_gather_ea(const int* __restrict__ seid, const float* __restrict__ edge_attr,
                            float* __restrict__ sea, int e_total) {
    int p = blockIdx.x * 256 + threadIdx.x;
    int ep = p >> 2, q = p & 3;
    if (ep < e_total) {
        int eid = seid[ep];
        ((float4*)sea)[ep * 4 + q] = ((const float4*)edge_attr)[eid * 4 + q];
    }
}

// ---------------- h = x @ Wp + bp  ([N,64]@[64,128]) ----------------

__global__ __launch_bounds__(256) void k_proj(const float* __restrict__ x, const float* __restrict__ Wp,
                                              const float* __restrict__ bp, float* __restrict__ h, int n) {
    __shared__ float shx[32 * 64];
    __shared__ float shw[64 * 128];
    int t = threadIdx.x;
    int row0 = blockIdx.x * 32;
    int nrows = min(32, n - row0);

    for (int i = t; i < 64 * 128 / 4; i += 256)
        ((float4*)shw)[i] = ((const float4*)Wp)[i];
    for (int i = t; i < 32 * 64 / 4; i += 256) {
        int r = i >> 4;
        float4 v = make_float4(0.f, 0.f, 0.f, 0.f);
        if (r < nrows) v = ((const float4*)x)[row0 * 16 + i];
        ((float4*)shx)[i] = v;
    }
    __syncthreads();

    int tr = (t >> 5) * 4;
    int tc = (t & 31) * 4;
    float acc[4][4];
    float4 b4 = *(const float4*)&bp[tc];
#pragma unroll
    for (int j = 0; j < 4; j++) { acc[j][0] = b4.x; acc[j][1] = b4.y; acc[j][2] = b4.z; acc[j][3] = b4.w; }

    for (int k = 0; k < 64; k++) {
        float4 w = *(float4*)&shw[k * 128 + tc];
#pragma unroll
        for (int j = 0; j < 4; j++) {
            float a = shx[(tr + j) * 64 + k];
            acc[j][0] = fmaf(a, w.x, acc[j][0]);
            acc[j][1] = fmaf(a, w.y, acc[j][1]);
            acc[j][2] = fmaf(a, w.z, acc[j][2]);
            acc[j][3] = fmaf(a, w.w, acc[j][3]);
        }
    }
#pragma unroll
    for (int j = 0; j < 4; j++) {
        int r = row0 + tr + j;
        if (r < n) {
            float4 o = make_float4(acc[j][0], acc[j][1], acc[j][2], acc[j][3]);
            *(float4*)&h[r * 128 + tc] = o;
        }
    }
}

// ---------------- fused LayerNorm + dual GEMM ----------------

__global__ __launch_bounds__(256) void k_ln_gemm(const float* __restrict__ h,
                                                 const float* __restrict__ lng, const float* __restrict__ lnb,
                                                 const float* __restrict__ Wl, const float* __restrict__ bl,
                                                 const float* __restrict__ Wr, const float* __restrict__ br,
                                                 float* __restrict__ xl, float* __restrict__ xr, int n) {
    __shared__ float shn[32 * 128];
    __shared__ float shwl[32 * 128];
    __shared__ float shwr[32 * 128];
    __shared__ float smu[32], srs[32];
    int t = threadIdx.x;
    int row0 = blockIdx.x * 32;
    int nrows = min(32, n - row0);

    for (int i = t; i < 1024; i += 256) {
        int r = i >> 5;
        float4 v = make_float4(0.f, 0.f, 0.f, 0.f);
        if (r < nrows) v = ((const float4*)h)[row0 * 32 + i];
        ((float4*)shn)[i] = v;
    }
    __syncthreads();

    {
        int r = t >> 3, sl = t & 7;
        float s = 0.f, ss = 0.f;
        for (int c = sl; c < 128; c += 8) {
            float v = shn[r * 128 + c];
            s += v; ss += v * v;
        }
#pragma unroll
        for (int o = 1; o < 8; o <<= 1) { s += __shfl_xor(s, o, 64); ss += __shfl_xor(ss, o, 64); }
        if (sl == 0) {
            float mu = s * (1.f / 128.f);
            float var = ss * (1.f / 128.f) - mu * mu;
            smu[r] = mu;
            srs[r] = rsqrtf(var + 1e-5f);
        }
    }
    __syncthreads();
    for (int i = t; i < 4096; i += 256) {
        int r = i >> 7, c = i & 127;
        shn[i] = (shn[i] - smu[r]) * srs[r] * lng[c] + lnb[c];
    }

    int tr = (t >> 5) * 4;
    int tc = (t & 31) * 4;
    float accl[4][4], accr[4][4];
    {
        float4 bl4 = *(const float4*)&bl[tc];
        float4 br4 = *(const float4*)&br[tc];
#pragma unroll
        for (int j = 0; j < 4; j++) {
            accl[j][0] = bl4.x; accl[j][1] = bl4.y; accl[j][2] = bl4.z; accl[j][3] = bl4.w;
            accr[j][0] = br4.x; accr[j][1] = br4.y; accr[j][2] = br4.z; accr[j][3] = br4.w;
        }
    }

    for (int kb = 0; kb < 4; kb++) {
        __syncthreads();
        for (int i = t; i < 1024; i += 256) {
            ((float4*)shwl)[i] = ((const float4*)Wl)[kb * 1024 + i];
            ((float4*)shwr)[i] = ((const float4*)Wr)[kb * 1024 + i];
        }
        __syncthreads();
#pragma unroll 8
        for (int kk = 0; kk < 32; kk++) {
            int k = kb * 32 + kk;
            float4 wl4 = *(float4*)&shwl[kk * 128 + tc];
            float4 wr4 = *(float4*)&shwr[kk * 128 + tc];
#pragma unroll
            for (int j = 0; j < 4; j++) {
                float a = shn[(tr + j) * 128 + k];
                accl[j][0] = fmaf(a, wl4.x, accl[j][0]);
                accl[j][1] = fmaf(a, wl4.y, accl[j][1]);
                accl[j][2] = fmaf(a, wl4.z, accl[j][2]);
                accl[j][3] = fmaf(a, wl4.w, accl[j][3]);
                accr[j][0] = fmaf(a, wr4.x, accr[j][0]);
                accr[j][1] = fmaf(a, wr4.y, accr[j][1]);
                accr[j][2] = fmaf(a, wr4.z, accr[j][2]);
                accr[j][3] = fmaf(a, wr4.w, accr[j][3]);
            }
        }
    }
#pragma unroll
    for (int j = 0; j < 4; j++) {
        int r = row0 + tr + j;
        if (r < n) {
            float4 ol = make_float4(accl[j][0], accl[j][1], accl[j][2], accl[j][3]);
            float4 orr = make_float4(accr[j][0], accr[j][1], accr[j][2], accr[j][3]);
            *(float4*)&xl[r * 128 + tc] = ol;
            *(float4*)&xr[r * 128 + tc] = orr;
        }
    }
}

// ---------------- GAT aggregate v4: persistent waves ----------------
// 2048 blocks x 4 waves = 8192 resident waves (32/CU); each wave grid-strides
// over nodes. We/att/bout register state loaded once per wave. 4-edge unroll,
// no online max (logits tiny, softmax shift-invariant).

__device__ __forceinline__ void ee16(const float4& c0, const float4& c1, const float4& c2, const float4& c3,
                                     const float2* we, float& e0, float& e1) {
    e0 = fmaf(c0.x, we[0].x, e0);  e1 = fmaf(c0.x, we[0].y, e1);
    e0 = fmaf(c0.y, we[1].x, e0);  e1 = fmaf(c0.y, we[1].y, e1);
    e0 = fmaf(c0.z, we[2].x, e0);  e1 = fmaf(c0.z, we[2].y, e1);
    e0 = fmaf(c0.w, we[3].x, e0);  e1 = fmaf(c0.w, we[3].y, e1);
    e0 = fmaf(c1.x, we[4].x, e0);  e1 = fmaf(c1.x, we[4].y, e1);
    e0 = fmaf(c1.y, we[5].x, e0);  e1 = fmaf(c1.y, we[5].y, e1);
    e0 = fmaf(c1.z, we[6].x, e0);  e1 = fmaf(c1.z, we[6].y, e1);
    e0 = fmaf(c1.w, we[7].x, e0);  e1 = fmaf(c1.w, we[7].y, e1);
    e0 = fmaf(c2.x, we[8].x, e0);  e1 = fmaf(c2.x, we[8].y, e1);
    e0 = fmaf(c2.y, we[9].x, e0);  e1 = fmaf(c2.y, we[9].y, e1);
    e0 = fmaf(c2.z, we[10].x, e0); e1 = fmaf(c2.z, we[10].y, e1);
    e0 = fmaf(c2.w, we[11].x, e0); e1 = fmaf(c2.w, we[11].y, e1);
    e0 = fmaf(c3.x, we[12].x, e0); e1 = fmaf(c3.x, we[12].y, e1);
    e0 = fmaf(c3.y, we[13].x, e0); e1 = fmaf(c3.y, we[13].y, e1);
    e0 = fmaf(c3.z, we[14].x, e0); e1 = fmaf(c3.z, we[14].y, e1);
    e0 = fmaf(c3.w, we[15].x, e0); e1 = fmaf(c3.w, we[15].y, e1);
}

__device__ __forceinline__ float lrelu(float v) { return v > 0.f ? v : 0.2f * v; }

#define AGG_BLOCKS 2048

template <bool SORTED>
__global__ __launch_bounds__(256) void k_gat_agg4(const float* __restrict__ xl, const float* __restrict__ xr,
                                                  const float* __restrict__ eattr,
                                                  const int* __restrict__ offs,
                                                  const int* __restrict__ seid, const int* __restrict__ ssrc,
                                                  const float* __restrict__ We, const float* __restrict__ att,
                                                  const float* __restrict__ bout, float* __restrict__ h, int n) {
    int wid = threadIdx.x >> 6;
    int lane = threadIdx.x & 63;
    int gwave = blockIdx.x * 4 + wid;
    const int nwaves = AGG_BLOCKS * 4;

    int chb = (lane >> 5) * 64 + (lane & 31) * 2;

    // wave-lifetime constants (loaded once)
    float2 we[16];
#pragma unroll
    for (int k = 0; k < 16; k++) we[k] = *(const float2*)&We[k * 128 + chb];
    float2 av = *(const float2*)&att[chb];
    float2 bo = *(const float2*)&bout[chb];

    for (int node = gwave; node < n; node += nwaves) {
        float2 xr2 = *(const float2*)&xr[node * 128 + chb];
        int s = offs[node], e = offs[node + 1];
        float den = 0.f, A0 = 0.f, A1 = 0.f;

        int j = s;
        for (; j + 4 <= e; j += 4) {
            int sa = ssrc[j], sb = ssrc[j + 1], sc2 = ssrc[j + 2], sd = ssrc[j + 3];
            float2 lxa = *(const float2*)&xl[sa * 128 + chb];
            float2 lxb = *(const float2*)&xl[sb * 128 + chb];
            float2 lxc = *(const float2*)&xl[sc2 * 128 + chb];
            float2 lxd = *(const float2*)&xl[sd * 128 + chb];
            const float4* eaA = (const float4*)&eattr[(size_t)(SORTED ? j : seid[j]) * 16];
            const float4* eaB = (const float4*)&eattr[(size_t)(SORTED ? j + 1 : seid[j + 1]) * 16];
            const float4* eaC = (const float4*)&eattr[(size_t)(SORTED ? j + 2 : seid[j + 2]) * 16];
            const float4* eaD = (const float4*)&eattr[(size_t)(SORTED ? j + 3 : seid[j + 3]) * 16];

            float ea0 = 0.f, ea1 = 0.f, eb0 = 0.f, eb1 = 0.f;
            float ec0 = 0.f, ec1 = 0.f, ed0 = 0.f, ed1 = 0.f;
            ee16(eaA[0], eaA[1], eaA[2], eaA[3], we, ea0, ea1);
            ee16(eaB[0], eaB[1], eaB[2], eaB[3], we, eb0, eb1);
            ee16(eaC[0], eaC[1], eaC[2], eaC[3], we, ec0, ec1);
            ee16(eaD[0], eaD[1], eaD[2], eaD[3], we, ed0, ed1);

            float pa = lrelu(lxa.x + xr2.x + ea0) * av.x + lrelu(lxa.y + xr2.y + ea1) * av.y;
            float pb = lrelu(lxb.x + xr2.x + eb0) * av.x + lrelu(lxb.y + xr2.y + eb1) * av.y;
            float pc = lrelu(lxc.x + xr2.x + ec0) * av.x + lrelu(lxc.y + xr2.y + ec1) * av.y;
            float pd = lrelu(lxd.x + xr2.x + ed0) * av.x + lrelu(lxd.y + xr2.y + ed1) * av.y;
#pragma unroll
            for (int o = 1; o <= 16; o <<= 1) {
                pa += __shfl_xor(pa, o, 64);
                pb += __shfl_xor(pb, o, 64);
                pc += __shfl_xor(pc, o, 64);
                pd += __shfl_xor(pd, o, 64);
            }
            float wa = __expf(pa), wb = __expf(pb), wc = __expf(pc), wd = __expf(pd);
            den += (wa + wb) + (wc + wd);
            A0 = fmaf(wa, lxa.x, fmaf(wb, lxb.x, fmaf(wc, lxc.x, fmaf(wd, lxd.x, A0))));
            A1 = fmaf(wa, lxa.y, fmaf(wb, lxb.y, fmaf(wc, lxc.y, fmaf(wd, lxd.y, A1))));
        }
        for (; j < e; j++) {
            int sa = ssrc[j];
            const float4* eaA = (const float4*)&eattr[(size_t)(SORTED ? j : seid[j]) * 16];
            float2 lxa = *(const float2*)&xl[sa * 128 + chb];
            float ea0 = 0.f, ea1 = 0.f;
            ee16(eaA[0], eaA[1], eaA[2], eaA[3], we, ea0, ea1);
            float pa = lrelu(lxa.x + xr2.x + ea0) * av.x + lrelu(lxa.y + xr2.y + ea1) * av.y;
#pragma unroll
            for (int o = 1; o <= 16; o <<= 1) pa += __shfl_xor(pa, o, 64);
            float wa = __expf(pa);
            den += wa;
            A0 = fmaf(wa, lxa.x, A0);
            A1 = fmaf(wa, lxa.y, A1);
        }

        float inv = (e > s) ? (1.f / den) : 0.f;
        float hg0 = fmaxf(fmaf(A0, inv, bo.x), 0.f);
        float hg1 = fmaxf(fmaf(A1, inv, bo.y), 0.f);
        float2* hp = (float2*)&h[node * 128 + chb];
        float2 hv = *hp;
        hv.x += hg0;
        hv.y += hg1;
        *hp = hv;
    }
}

// ---------------- classifier + embedding write ----------------

__global__ __launch_bounds__(256) void k_cls(const float* __restrict__ h, const float* __restrict__ Wc,
                                             const float* __restrict__ bc,
                                             float* __restrict__ out_cls, float* __restrict__ out_emb, int n) {
    int wid = threadIdx.x >> 6;
    int lane = threadIdx.x & 63;
    int node = blockIdx.x * 4 + wid;
    if (node >= n) return;
    float h0 = h[(size_t)node * 128 + lane];
    float h1 = h[(size_t)node * 128 + 64 + lane];
    float p[10];
#pragma unroll
    for (int k = 0; k < 10; k++) p[k] = h0 * Wc[lane * 10 + k] + h1 * Wc[(64 + lane) * 10 + k];
#pragma unroll
    for (int o = 32; o; o >>= 1) {
#pragma unroll
        for (int k = 0; k < 10; k++) p[k] += __shfl_xor(p[k], o, 64);
    }
    if (lane == 0) {
#pragma unroll
        for (int k = 0; k < 10; k++) out_cls[(size_t)node * 10 + k] = p[k] + bc[k];
    }
    out_emb[(size_t)node * 128 + lane] = h0;
    out_emb[(size_t)node * 128 + 64 + lane] = h1;
}

extern "C" void kernel_launch(void* const* d_in, const int* in_sizes, int n_in,
                              void* d_out, int out_size, void* d_ws, size_t ws_size,
                              hipStream_t stream) {
    const float* x         = (const float*)d_in[0];
    const int*   edge_idx  = (const int*)d_in[1];
    const float* edge_attr = (const float*)d_in[2];
    const float* Wp        = (const float*)d_in[3];
    const float* bp        = (const float*)d_in[4];
    const float* lng       = (const float*)d_in[5];
    const float* lnb       = (const float*)d_in[6];
    const float* Wl        = (const float*)d_in[7];
    const float* bl        = (const float*)d_in[8];
    const float* Wr        = (const float*)d_in[9];
    const float* br        = (const float*)d_in[10];
    const float* We        = (const float*)d_in[11];
    const float* att       = (const float*)d_in[12];
    const float* bout      = (const float*)d_in[13];
    const float* Wc        = (const float*)d_in[14];
    const float* bc        = (const float*)d_in[15];

    const int N = N_NODES, E = N_EDGES;

    char* w = (char*)d_ws;
    size_t used = 0;
    auto take = [&](size_t bytes) -> void* {
        void* p = (void*)(w + used);
        used += (bytes + 255) & ~(size_t)255;
        return p;
    };
    float* h      = (float*)take((size_t)N * 128 * 4);
    float* xl     = (float*)take((size_t)N * 128 * 4);
    float* xr     = (float*)take((size_t)N * 128 * 4);
    int*   indeg  = (int*)take((size_t)N * 4);
    int*   offs   = (int*)take((size_t)(N + 1) * 4);
    int*   cursor = (int*)take((size_t)N * 4);
    int*   bsum   = (int*)take(64 * 4);
    int*   seid   = (int*)take((size_t)E * 4);
    int*   ssrc   = (int*)take((size_t)E * 4);
    float* sea    = (float*)take((size_t)E * 16 * 4);
    bool sorted_ok = (used <= ws_size);

    const int* srcArr = edge_idx;
    const int* dstArr = edge_idx + E;

    hipMemsetAsync(indeg, 0, (size_t)N * 4, stream);
    k_count<<<(E + 255) / 256, 256, 0, stream>>>(dstArr, indeg, E);
    int NB = (N + 1023) / 1024;
    k_scan_block<<<NB, 1024, 0, stream>>>(indeg, offs, bsum, N);
    k_scan_small<<<1, 64, 0, stream>>>(bsum, NB);
    k_scan_add<<<NB, 1024, 0, stream>>>(offs, bsum, cursor, N, E);
    k_scatter<<<(E + 255) / 256, 256, 0, stream>>>(srcArr, dstArr, cursor, seid, ssrc, E);
    if (sorted_ok)
        k_gather_ea<<<(E * 4 + 255) / 256, 256, 0, stream>>>(seid, edge_attr, sea, E);

    k_proj<<<(N + 31) / 32, 256, 0, stream>>>(x, Wp, bp, h, N);

    for (int i = 0; i < 2; i++) {
        k_ln_gemm<<<(N + 31) / 32, 256, 0, stream>>>(
            h, lng + i * 128, lnb + i * 128,
            Wl + (size_t)i * 128 * 128, bl + i * 128,
            Wr + (size_t)i * 128 * 128, br + i * 128,
            xl, xr, N);
        if (sorted_ok)
            k_gat_agg4<true><<<AGG_BLOCKS, 256, 0, stream>>>(
                xl, xr, sea, offs, seid, ssrc,
                We + (size_t)i * 16 * 128, att + i * 128, bout + i * 128, h, N);
        else
            k_gat_agg4<false><<<AGG_BLOCKS, 256, 0, stream>>>(
                xl, xr, edge_attr, offs, seid, ssrc,
                We + (size_t)i * 16 * 128, att + i * 128, bout + i * 128, h, N);
    }

    k_cls<<<(N + 3) / 4, 256, 0, stream>>>(h, Wc, bc, (float*)d_out, (float*)d_out + (size_t)N * KCLS, N);
}

// Round 6
// 494.417 us; speedup vs baseline: 1.3507x; 1.2474x over previous
//
#include <hip/hip_runtime.h>
#include <math.h>

#define N_NODES 50000
#define N_EDGES 800000
#define FDIM 128
#define KCLS 10

typedef float v2f __attribute__((ext_vector_type(2)));

__device__ __forceinline__ v2f pksplat(float a) { v2f r; r.x = a; r.y = a; return r; }
__device__ __forceinline__ v2f pkfma(v2f a, v2f b, v2f c) { return __builtin_elementwise_fma(a, b, c); }
__device__ __forceinline__ v2f pklrelu(v2f v) {
    v2f z = pksplat(0.f);
    v2f mx = __builtin_elementwise_max(v, z);
    v2f mn = __builtin_elementwise_min(v, z);
    return pkfma(pksplat(0.2f), mn, mx);
}

// ---------------- CSR build ----------------

__global__ void k_count(const int* __restrict__ dst, int* __restrict__ indeg, int e_total) {
    int e = blockIdx.x * 256 + threadIdx.x;
    if (e < e_total) atomicAdd(&indeg[dst[e]], 1);
}

__global__ __launch_bounds__(1024) void k_scan_block(const int* __restrict__ in, int* __restrict__ excl,
                                                     int* __restrict__ bsum, int n) {
    __shared__ int sh[1024];
    int t = threadIdx.x;
    int g = blockIdx.x * 1024 + t;
    int v = (g < n) ? in[g] : 0;
    sh[t] = v;
    __syncthreads();
    for (int d = 1; d < 1024; d <<= 1) {
        int x = (t >= d) ? sh[t - d] : 0;
        __syncthreads();
        sh[t] += x;
        __syncthreads();
    }
    if (g < n) excl[g] = sh[t] - v;
    if (t == 1023) bsum[blockIdx.x] = sh[t];
}

__global__ void k_scan_small(int* bsum, int nb) {
    if (threadIdx.x == 0 && blockIdx.x == 0) {
        int run = 0;
        for (int i = 0; i < nb; i++) { int v = bsum[i]; bsum[i] = run; run += v; }
    }
}

__global__ __launch_bounds__(1024) void k_scan_add(int* __restrict__ offs, const int* __restrict__ bsum,
                                                   int* __restrict__ cursor, int n, int e_total) {
    int g = blockIdx.x * 1024 + threadIdx.x;
    if (g < n) {
        int v = offs[g] + bsum[blockIdx.x];
        offs[g] = v;
        cursor[g] = v;
    }
    if (g == 0) offs[n] = e_total;
}

__global__ void k_scatter(const int* __restrict__ src, const int* __restrict__ dst,
                          int* __restrict__ cursor, int* __restrict__ seid, int* __restrict__ ssrc, int e_total) {
    int e = blockIdx.x * 256 + threadIdx.x;
    if (e < e_total) {
        int d = dst[e];
        int p = atomicAdd(&cursor[d], 1);
        seid[p] = e;
        ssrc[p] = src[e];
    }
}

// copy edge_attr into CSR (sorted) order
__global__ void k_gather_ea(const int* __restrict__ seid, const float* __restrict__ edge_attr,
                            float* __restrict__ sea, int e_total) {
    int p = blockIdx.x * 256 + threadIdx.x;
    int ep = p >> 2, q = p & 3;
    if (ep < e_total) {
        int eid = seid[ep];
        ((float4*)sea)[ep * 4 + q] = ((const float4*)edge_attr)[eid * 4 + q];
    }
}

// ---------------- h = x @ Wp + bp  ([N,64]@[64,128]) ----------------

__global__ __launch_bounds__(256) void k_proj(const float* __restrict__ x, const float* __restrict__ Wp,
                                              const float* __restrict__ bp, float* __restrict__ h, int n) {
    __shared__ float shx[32 * 64];
    __shared__ float shw[64 * 128];
    int t = threadIdx.x;
    int row0 = blockIdx.x * 32;
    int nrows = min(32, n - row0);

    for (int i = t; i < 64 * 128 / 4; i += 256)
        ((float4*)shw)[i] = ((const float4*)Wp)[i];
    for (int i = t; i < 32 * 64 / 4; i += 256) {
        int r = i >> 4;
        float4 v = make_float4(0.f, 0.f, 0.f, 0.f);
        if (r < nrows) v = ((const float4*)x)[row0 * 16 + i];
        ((float4*)shx)[i] = v;
    }
    __syncthreads();

    int tr = (t >> 5) * 4;
    int tc = (t & 31) * 4;
    float acc[4][4];
    float4 b4 = *(const float4*)&bp[tc];
#pragma unroll
    for (int j = 0; j < 4; j++) { acc[j][0] = b4.x; acc[j][1] = b4.y; acc[j][2] = b4.z; acc[j][3] = b4.w; }

    for (int k = 0; k < 64; k++) {
        float4 w = *(float4*)&shw[k * 128 + tc];
#pragma unroll
        for (int j = 0; j < 4; j++) {
            float a = shx[(tr + j) * 64 + k];
            acc[j][0] = fmaf(a, w.x, acc[j][0]);
            acc[j][1] = fmaf(a, w.y, acc[j][1]);
            acc[j][2] = fmaf(a, w.z, acc[j][2]);
            acc[j][3] = fmaf(a, w.w, acc[j][3]);
        }
    }
#pragma unroll
    for (int j = 0; j < 4; j++) {
        int r = row0 + tr + j;
        if (r < n) {
            float4 o = make_float4(acc[j][0], acc[j][1], acc[j][2], acc[j][3]);
            *(float4*)&h[r * 128 + tc] = o;
        }
    }
}

// ---------------- fused LayerNorm + dual GEMM ----------------

__global__ __launch_bounds__(256) void k_ln_gemm(const float* __restrict__ h,
                                                 const float* __restrict__ lng, const float* __restrict__ lnb,
                                                 const float* __restrict__ Wl, const float* __restrict__ bl,
                                                 const float* __restrict__ Wr, const float* __restrict__ br,
                                                 float* __restrict__ xl, float* __restrict__ xr, int n) {
    __shared__ float shn[32 * 128];
    __shared__ float shwl[32 * 128];
    __shared__ float shwr[32 * 128];
    __shared__ float smu[32], srs[32];
    int t = threadIdx.x;
    int row0 = blockIdx.x * 32;
    int nrows = min(32, n - row0);

    for (int i = t; i < 1024; i += 256) {
        int r = i >> 5;
        float4 v = make_float4(0.f, 0.f, 0.f, 0.f);
        if (r < nrows) v = ((const float4*)h)[row0 * 32 + i];
        ((float4*)shn)[i] = v;
    }
    __syncthreads();

    {
        int r = t >> 3, sl = t & 7;
        float s = 0.f, ss = 0.f;
        for (int c = sl; c < 128; c += 8) {
            float v = shn[r * 128 + c];
            s += v; ss += v * v;
        }
#pragma unroll
        for (int o = 1; o < 8; o <<= 1) { s += __shfl_xor(s, o, 64); ss += __shfl_xor(ss, o, 64); }
        if (sl == 0) {
            float mu = s * (1.f / 128.f);
            float var = ss * (1.f / 128.f) - mu * mu;
            smu[r] = mu;
            srs[r] = rsqrtf(var + 1e-5f);
        }
    }
    __syncthreads();
    for (int i = t; i < 4096; i += 256) {
        int r = i >> 7, c = i & 127;
        shn[i] = (shn[i] - smu[r]) * srs[r] * lng[c] + lnb[c];
    }

    int tr = (t >> 5) * 4;
    int tc = (t & 31) * 4;
    float accl[4][4], accr[4][4];
    {
        float4 bl4 = *(const float4*)&bl[tc];
        float4 br4 = *(const float4*)&br[tc];
#pragma unroll
        for (int j = 0; j < 4; j++) {
            accl[j][0] = bl4.x; accl[j][1] = bl4.y; accl[j][2] = bl4.z; accl[j][3] = bl4.w;
            accr[j][0] = br4.x; accr[j][1] = br4.y; accr[j][2] = br4.z; accr[j][3] = br4.w;
        }
    }

    for (int kb = 0; kb < 4; kb++) {
        __syncthreads();
        for (int i = t; i < 1024; i += 256) {
            ((float4*)shwl)[i] = ((const float4*)Wl)[kb * 1024 + i];
            ((float4*)shwr)[i] = ((const float4*)Wr)[kb * 1024 + i];
        }
        __syncthreads();
#pragma unroll 8
        for (int kk = 0; kk < 32; kk++) {
            int k = kb * 32 + kk;
            float4 wl4 = *(float4*)&shwl[kk * 128 + tc];
            float4 wr4 = *(float4*)&shwr[kk * 128 + tc];
#pragma unroll
            for (int j = 0; j < 4; j++) {
                float a = shn[(tr + j) * 128 + k];
                accl[j][0] = fmaf(a, wl4.x, accl[j][0]);
                accl[j][1] = fmaf(a, wl4.y, accl[j][1]);
                accl[j][2] = fmaf(a, wl4.z, accl[j][2]);
                accl[j][3] = fmaf(a, wl4.w, accl[j][3]);
                accr[j][0] = fmaf(a, wr4.x, accr[j][0]);
                accr[j][1] = fmaf(a, wr4.y, accr[j][1]);
                accr[j][2] = fmaf(a, wr4.z, accr[j][2]);
                accr[j][3] = fmaf(a, wr4.w, accr[j][3]);
            }
        }
    }
#pragma unroll
    for (int j = 0; j < 4; j++) {
        int r = row0 + tr + j;
        if (r < n) {
            float4 ol = make_float4(accl[j][0], accl[j][1], accl[j][2], accl[j][3]);
            float4 orr = make_float4(accr[j][0], accr[j][1], accr[j][2], accr[j][3]);
            *(float4*)&xl[r * 128 + tc] = ol;
            *(float4*)&xr[r * 128 + tc] = orr;
        }
    }
}

// ---------------- GAT aggregate v5: persistent + scalar-ized + packed fp32 ----------------
// Wave-uniform values (edge range, ssrc, eattr rows) forced to SGPRs via
// readfirstlane -> scalar loads + saddr-form gathers; all channel math on
// float2 (v_pk_fma_f32). 4-edge unroll, no online max.

#define AGG_BLOCKS 1536

template <bool SORTED>
__global__ __launch_bounds__(256, 6) void k_gat_agg5(const float* __restrict__ xl, const float* __restrict__ xr,
                                                     const float* __restrict__ eattr,
                                                     const int* __restrict__ offs,
                                                     const int* __restrict__ seid, const int* __restrict__ ssrc,
                                                     const float* __restrict__ We, const float* __restrict__ att,
                                                     const float* __restrict__ bout, float* __restrict__ h, int n) {
    int wid = threadIdx.x >> 6;
    int lane = threadIdx.x & 63;
    int gwave = blockIdx.x * 4 + wid;
    const int nwaves = AGG_BLOCKS * 4;

    int chb = (lane >> 5) * 64 + (lane & 31) * 2;
    const float* xl_lane = xl + chb;  // per-lane base; row offset added as uniform

    v2f we[16];
#pragma unroll
    for (int k = 0; k < 16; k++) we[k] = *(const v2f*)&We[k * 128 + chb];
    v2f av = *(const v2f*)&att[chb];
    v2f bo = *(const v2f*)&bout[chb];

    for (int node = gwave; node < n; node += nwaves) {
        v2f xr2 = *(const v2f*)&xr[node * 128 + chb];
        int s = __builtin_amdgcn_readfirstlane(offs[node]);
        int e = __builtin_amdgcn_readfirstlane(offs[node + 1]);
        float den = 0.f;
        v2f A = pksplat(0.f);

        int j = s;
        for (; j + 4 <= e; j += 4) {
            int sa = __builtin_amdgcn_readfirstlane(ssrc[j]);
            int sb = __builtin_amdgcn_readfirstlane(ssrc[j + 1]);
            int sc2 = __builtin_amdgcn_readfirstlane(ssrc[j + 2]);
            int sd = __builtin_amdgcn_readfirstlane(ssrc[j + 3]);
            v2f lxa = *(const v2f*)(xl_lane + sa * 128);
            v2f lxb = *(const v2f*)(xl_lane + sb * 128);
            v2f lxc = *(const v2f*)(xl_lane + sc2 * 128);
            v2f lxd = *(const v2f*)(xl_lane + sd * 128);

            int ra = SORTED ? j : __builtin_amdgcn_readfirstlane(seid[j]);
            int rb = SORTED ? j + 1 : __builtin_amdgcn_readfirstlane(seid[j + 1]);
            int rc = SORTED ? j + 2 : __builtin_amdgcn_readfirstlane(seid[j + 2]);
            int rd = SORTED ? j + 3 : __builtin_amdgcn_readfirstlane(seid[j + 3]);
            const float* eA = &eattr[(size_t)ra * 16];
            const float* eB = &eattr[(size_t)rb * 16];
            const float* eC = &eattr[(size_t)rc * 16];
            const float* eD = &eattr[(size_t)rd * 16];

            v2f va = lxa + xr2;
            v2f vb = lxb + xr2;
            v2f vc = lxc + xr2;
            v2f vd = lxd + xr2;
#pragma unroll
            for (int k = 0; k < 16; k++) {
                va = pkfma(pksplat(eA[k]), we[k], va);
                vb = pkfma(pksplat(eB[k]), we[k], vb);
                vc = pkfma(pksplat(eC[k]), we[k], vc);
                vd = pkfma(pksplat(eD[k]), we[k], vd);
            }
            va = pklrelu(va);
            vb = pklrelu(vb);
            vc = pklrelu(vc);
            vd = pklrelu(vd);
            v2f ta = va * av, tb = vb * av, tc2 = vc * av, td = vd * av;
            float pa = ta.x + ta.y;
            float pb = tb.x + tb.y;
            float pc = tc2.x + tc2.y;
            float pd = td.x + td.y;
#pragma unroll
            for (int o = 1; o <= 16; o <<= 1) {
                pa += __shfl_xor(pa, o, 64);
                pb += __shfl_xor(pb, o, 64);
                pc += __shfl_xor(pc, o, 64);
                pd += __shfl_xor(pd, o, 64);
            }
            float wa = __expf(pa), wb = __expf(pb), wc = __expf(pc), wd = __expf(pd);
            den += (wa + wb) + (wc + wd);
            A = pkfma(pksplat(wa), lxa, A);
            A = pkfma(pksplat(wb), lxb, A);
            A = pkfma(pksplat(wc), lxc, A);
            A = pkfma(pksplat(wd), lxd, A);
        }
        for (; j < e; j++) {
            int sa = __builtin_amdgcn_readfirstlane(ssrc[j]);
            v2f lxa = *(const v2f*)(xl_lane + sa * 128);
            int ra = SORTED ? j : __builtin_amdgcn_readfirstlane(seid[j]);
            const float* eA = &eattr[(size_t)ra * 16];
            v2f va = lxa + xr2;
#pragma unroll
            for (int k = 0; k < 16; k++) va = pkfma(pksplat(eA[k]), we[k], va);
            va = pklrelu(va);
            v2f ta = va * av;
            float pa = ta.x + ta.y;
#pragma unroll
            for (int o = 1; o <= 16; o <<= 1) pa += __shfl_xor(pa, o, 64);
            float wa = __expf(pa);
            den += wa;
            A = pkfma(pksplat(wa), lxa, A);
        }

        float inv = (e > s) ? (1.f / den) : 0.f;
        v2f hg = pkfma(A, pksplat(inv), bo);
        hg = __builtin_elementwise_max(hg, pksplat(0.f));
        v2f* hp = (v2f*)&h[node * 128 + chb];
        *hp = *hp + hg;
    }
}

// ---------------- classifier + embedding write ----------------

__global__ __launch_bounds__(256) void k_cls(const float* __restrict__ h, const float* __restrict__ Wc,
                                             const float* __restrict__ bc,
                                             float* __restrict__ out_cls, float* __restrict__ out_emb, int n) {
    int wid = threadIdx.x >> 6;
    int lane = threadIdx.x & 63;
    int node = blockIdx.x * 4 + wid;
    if (node >= n) return;
    float h0 = h[(size_t)node * 128 + lane];
    float h1 = h[(size_t)node * 128 + 64 + lane];
    float p[10];
#pragma unroll
    for (int k = 0; k < 10; k++) p[k] = h0 * Wc[lane * 10 + k] + h1 * Wc[(64 + lane) * 10 + k];
#pragma unroll
    for (int o = 32; o; o >>= 1) {
#pragma unroll
        for (int k = 0; k < 10; k++) p[k] += __shfl_xor(p[k], o, 64);
    }
    if (lane == 0) {
#pragma unroll
        for (int k = 0; k < 10; k++) out_cls[(size_t)node * 10 + k] = p[k] + bc[k];
    }
    out_emb[(size_t)node * 128 + lane] = h0;
    out_emb[(size_t)node * 128 + 64 + lane] = h1;
}

extern "C" void kernel_launch(void* const* d_in, const int* in_sizes, int n_in,
                              void* d_out, int out_size, void* d_ws, size_t ws_size,
                              hipStream_t stream) {
    const float* x         = (const float*)d_in[0];
    const int*   edge_idx  = (const int*)d_in[1];
    const float* edge_attr = (const float*)d_in[2];
    const float* Wp        = (const float*)d_in[3];
    const float* bp        = (const float*)d_in[4];
    const float* lng       = (const float*)d_in[5];
    const float* lnb       = (const float*)d_in[6];
    const float* Wl        = (const float*)d_in[7];
    const float* bl        = (const float*)d_in[8];
    const float* Wr        = (const float*)d_in[9];
    const float* br        = (const float*)d_in[10];
    const float* We        = (const float*)d_in[11];
    const float* att       = (const float*)d_in[12];
    const float* bout      = (const float*)d_in[13];
    const float* Wc        = (const float*)d_in[14];
    const float* bc        = (const float*)d_in[15];

    const int N = N_NODES, E = N_EDGES;

    char* w = (char*)d_ws;
    size_t used = 0;
    auto take = [&](size_t bytes) -> void* {
        void* p = (void*)(w + used);
        used += (bytes + 255) & ~(size_t)255;
        return p;
    };
    float* h      = (float*)take((size_t)N * 128 * 4);
    float* xl     = (float*)take((size_t)N * 128 * 4);
    float* xr     = (float*)take((size_t)N * 128 * 4);
    int*   indeg  = (int*)take((size_t)N * 4);
    int*   offs   = (int*)take((size_t)(N + 1) * 4);
    int*   cursor = (int*)take((size_t)N * 4);
    int*   bsum   = (int*)take(64 * 4);
    int*   seid   = (int*)take((size_t)E * 4);
    int*   ssrc   = (int*)take((size_t)E * 4);
    float* sea    = (float*)take((size_t)E * 16 * 4);
    bool sorted_ok = (used <= ws_size);

    const int* srcArr = edge_idx;
    const int* dstArr = edge_idx + E;

    (void)hipMemsetAsync(indeg, 0, (size_t)N * 4, stream);
    k_count<<<(E + 255) / 256, 256, 0, stream>>>(dstArr, indeg, E);
    int NB = (N + 1023) / 1024;
    k_scan_block<<<NB, 1024, 0, stream>>>(indeg, offs, bsum, N);
    k_scan_small<<<1, 64, 0, stream>>>(bsum, NB);
    k_scan_add<<<NB, 1024, 0, stream>>>(offs, bsum, cursor, N, E);
    k_scatter<<<(E + 255) / 256, 256, 0, stream>>>(srcArr, dstArr, cursor, seid, ssrc, E);
    if (sorted_ok)
        k_gather_ea<<<(E * 4 + 255) / 256, 256, 0, stream>>>(seid, edge_attr, sea, E);

    k_proj<<<(N + 31) / 32, 256, 0, stream>>>(x, Wp, bp, h, N);

    for (int i = 0; i < 2; i++) {
        k_ln_gemm<<<(N + 31) / 32, 256, 0, stream>>>(
            h, lng + i * 128, lnb + i * 128,
            Wl + (size_t)i * 128 * 128, bl + i * 128,
            Wr + (size_t)i * 128 * 128, br + i * 128,
            xl, xr, N);
        if (sorted_ok)
            k_gat_agg5<true><<<AGG_BLOCKS, 256, 0, stream>>>(
                xl, xr, sea, offs, seid, ssrc,
                We + (size_t)i * 16 * 128, att + i * 128, bout + i * 128, h, N);
        else
            k_gat_agg5<false><<<AGG_BLOCKS, 256, 0, stream>>>(
                xl, xr, edge_attr, offs, seid, ssrc,
                We + (size_t)i * 16 * 128, att + i * 128, bout + i * 128, h, N);
    }

    k_cls<<<(N + 3) / 4, 256, 0, stream>>>(h, Wc, bc, (float*)d_out, (float*)d_out + (size_t)N * KCLS, N);
}